// Round 15
// baseline (1506.995 us; speedup 1.0000x reference)
//
#include <hip/hip_runtime.h>

// DeformConv2d forward, fp32. B=8, C=64, H=W=128, N=9 (3x3), OC=128, pad=1.
//
// v6: software-pipelined main kernel (T14): per chunk, next chunk's corner
//     loads are issued into REGISTERS before the current chunk's GEMM, and
//     reduced+written to LDS after it -> global latency hides under 2.3K cyc
//     of FMAs. c-chunk = 4 channels (16 chunks) to keep in-flight VGPRs ~48.
//     Gather/GEMM instruction counts identical to v5; only the schedule moved.
//
// ws layout (floats):
//   wT   : [576][20]          offset-conv weights^T                    11520
//   wP   : [n*64+c][o]        main weights, o-contiguous               73728
//   offp : [2][b][9][HW][2]   partial offsets (c-halves)             4718592
//   xT   : [b][hw][c]         NHWC input                             8388608
// total = 13,192,448 floats = 52.8 MB

#define HW    16384
#define CIN   64
#define OC    128

constexpr int WT_OFF   = 0;
constexpr int WP_OFF   = 11520;
constexpr int OFF_OFF  = WP_OFF + 73728;           // 85248
constexpr int OFF_HALF = 8 * 9 * HW * 2;           // 2359296
constexpr int XT_OFF   = OFF_OFF + 2 * OFF_HALF;   // 4803840

__device__ __forceinline__ float clamp129(float v) {
  return fminf(fmaxf(v, 0.f), 129.f);
}

// Bilinear params, exact reference semantics (130x130 padded frame, clip to
// [0,129]; pad cells contribute zero -> folded into g=0).
__device__ __forceinline__ void bilin_params(int row, int col, int n,
                                             float ox, float oy,
                                             float4& g, int4& idx) {
  float px = (float)(row + n / 3 - 1) + ox;
  float py = (float)(col + n % 3 - 1) + oy;
  float fx = floorf(px), fy = floorf(py);
  float qltx = clamp129(fx),       qlty = clamp129(fy);
  float qrbx = clamp129(fx + 1.f), qrby = clamp129(fy + 1.f);
  float pcx = clamp129(px),        pcy = clamp129(py);
  float dltx = 1.f + qltx - pcx, dlty = 1.f + qlty - pcy;
  float drbx = 1.f - qrbx + pcx, drby = 1.f - qrby + pcy;
  float gg[4] = {dltx * dlty, drbx * drby, dltx * drby, drbx * dlty};
  int rr[4]   = {(int)qltx, (int)qrbx, (int)qltx, (int)qrbx};
  int cc[4]   = {(int)qlty, (int)qrby, (int)qrby, (int)qlty};
  int ii[4];
#pragma unroll
  for (int k = 0; k < 4; ++k) {
    bool v = (rr[k] >= 1) && (rr[k] <= 128) && (cc[k] >= 1) && (cc[k] <= 128);
    ii[k] = v ? ((rr[k] - 1) * 128 + (cc[k] - 1)) : 0;
    if (!v) gg[k] = 0.f;
  }
  g   = make_float4(gg[0], gg[1], gg[2], gg[3]);
  idx = make_int4(ii[0], ii[1], ii[2], ii[3]);
}

// ---------------- kernel 0: weight repack ----------------
__global__ __launch_bounds__(256) void repack_kernel(
    const float* __restrict__ w_conv, const float* __restrict__ w_p,
    float* __restrict__ wP, float* __restrict__ wT) {
  int i = blockIdx.x * 256 + threadIdx.x;
  if (i < 73728) {
    // wP[(n*64+c)*128 + o] = w_conv[o][c][n]
    int o = i & 127, m = i >> 7, n = m >> 6, c = m & 63;
    wP[i] = w_conv[o * 576 + c * 9 + n];
  }
  int j = i - 73728;
  if (j >= 0 && j < 11520) {
    int m = j / 20, n2 = j - m * 20;  // wT[m*20+n2] = w_p[n2*576+m]
    wT[j] = (n2 < 18) ? w_p[n2 * 576 + m] : 0.f;
  }
}

// ---------------- kernel 1: NCHW -> NHWC transpose ----------------
__global__ __launch_bounds__(256) void transpose_kernel(
    const float* __restrict__ x, float* __restrict__ xT) {
  __shared__ float t[64][65];
  const int b   = blockIdx.y;
  const int hw0 = blockIdx.x * 64;
  const int tid = threadIdx.x;
  {
    const int hwi = tid & 63, cq = tid >> 6;
    const float* xb = x + b * (CIN * HW);
#pragma unroll
    for (int k = 0; k < 16; ++k) {
      int c = cq * 16 + k;
      t[hwi][c] = xb[c * HW + hw0 + hwi];   // coalesced over hwi
    }
  }
  __syncthreads();
  {
    const int ci = tid & 63, hq = tid >> 6;
    float* xTb = xT + ((size_t)b * HW + hw0) * CIN;
#pragma unroll
    for (int k = 0; k < 16; ++k) {
      int hwi = hq * 16 + k;
      xTb[hwi * CIN + ci] = t[hwi][ci];     // coalesced over ci
    }
  }
}

// ---------------- kernel 2: offset conv, c-split x2 ----------------
__global__ __launch_bounds__(256) void offs_kernel(
    const float* __restrict__ x, const float* __restrict__ wT,
    float* __restrict__ offp) {
  const int half = blockIdx.z;
  const int b    = blockIdx.y;
  const int hw   = blockIdx.x * 256 + threadIdx.x;
  const int row  = hw >> 7;
  const int w    = hw & 127;

  float acc[18];
#pragma unroll
  for (int i = 0; i < 18; ++i) acc[i] = 0.f;

  const float* xb = x + b * (CIN * HW);
  const int c0 = half * 32;
  for (int ci = c0; ci < c0 + 32; ++ci) {
    const float* xs = xb + ci * HW;
#pragma unroll
    for (int kh = 0; kh < 3; ++kh) {
      int r = row + kh - 1;
      bool vr = (unsigned)r < 128u;
      int base = r * 128 + w;
      float rbv[3];
      rbv[0] = (vr && w >= 1)   ? xs[base - 1] : 0.f;
      rbv[1] = vr               ? xs[base]     : 0.f;
      rbv[2] = (vr && w <= 126) ? xs[base + 1] : 0.f;
#pragma unroll
      for (int kw = 0; kw < 3; ++kw) {
        const float* wr = wT + (ci * 9 + kh * 3 + kw) * 20;  // wave-uniform
        float xv = rbv[kw];
#pragma unroll
        for (int n2 = 0; n2 < 18; ++n2)
          acc[n2] = fmaf(xv, wr[n2], acc[n2]);
      }
    }
  }

  float* dst = offp + half * OFF_HALF;
#pragma unroll
  for (int n = 0; n < 9; ++n) {
    *(float2*)(dst + ((b * 9 + n) * HW + hw) * 2) =
        make_float2(acc[n], acc[n + 9]);
  }
}

// 4 corner float4s (4 channels) for one gather item
struct C4 { float4 a, b, c, d; };

__device__ __forceinline__ void gload(const float* __restrict__ xTb,
                                      const int4& I, int c0, C4& L) {
  L.a = *(const float4*)(xTb + I.x * CIN + c0);
  L.b = *(const float4*)(xTb + I.y * CIN + c0);
  L.c = *(const float4*)(xTb + I.z * CIN + c0);
  L.d = *(const float4*)(xTb + I.w * CIN + c0);
}

__device__ __forceinline__ void redw(const C4& L, const float4& G,
                                     float* __restrict__ dst) {
  dst[0]    = G.x * L.a.x + G.y * L.b.x + G.z * L.c.x + G.w * L.d.x;
  dst[576]  = G.x * L.a.y + G.y * L.b.y + G.z * L.c.y + G.w * L.d.y;
  dst[1152] = G.x * L.a.z + G.y * L.b.z + G.z * L.c.z + G.w * L.d.z;
  dst[1728] = G.x * L.a.w + G.y * L.b.w + G.z * L.c.w + G.w * L.d.w;
}

// ---------------- kernel 3: pipelined gather + o-sliced GEMM ----------------
// block: 64 px, 256 threads = 4 waves; wave w computes o in [32w, 32w+32) for
// all 64 px. 16 c-chunks of 4; chunk cc+1's corner loads are issued into regs
// before chunk cc's GEMM (latency hidden under FMAs), reduced to LDS after.
__global__ __launch_bounds__(256) void main_kernel(
    const float* __restrict__ xT, const float* __restrict__ wP,
    const float* __restrict__ offp, const float* __restrict__ b_p,
    float* __restrict__ out) {
  __shared__ __align__(16) float xlds[4 * 576];

  const int b    = blockIdx.y;
  const int px0  = blockIdx.x * 64;
  const int tid  = threadIdx.x;
  const int lane = tid & 63;
  const bool has3 = (tid < 64);  // 576 items over 256 threads: 2 or 3 each

  // wave-uniform o-slice base -> scalar weight loads
  const int ow_u = __builtin_amdgcn_readfirstlane((tid >> 6) * 32);
  const float* __restrict__ wPu = wP + ow_u;

  // --- per-thread bilinear params for items t = tid, tid+256, tid+512 ---
  float4 g0, g1, g2 = make_float4(0.f, 0.f, 0.f, 0.f);
  int4   i0, i1, i2 = make_int4(0, 0, 0, 0);
  {
    const float* oh0 = offp;
    const float* oh1 = offp + OFF_HALF;
#pragma unroll
    for (int j = 0; j < 3; ++j) {
      if (j == 2 && !has3) break;
      int t = tid + j * 256;          // n = t>>6, pxi = t&63
      int n = t >> 6, hw = px0 + (t & 63);
      int oidx = ((b * 9 + n) * HW + hw) * 2;
      float2 pa = *(const float2*)(oh0 + oidx);
      float2 pb = *(const float2*)(oh1 + oidx);
      float ox = pa.x + pb.x + b_p[n];
      float oy = pa.y + pb.y + b_p[n + 9];
      float4 g; int4 ii;
      bilin_params(hw >> 7, hw & 127, n, ox, oy, g, ii);
      if (j == 0) { g0 = g; i0 = ii; }
      else if (j == 1) { g1 = g; i1 = ii; }
      else { g2 = g; i2 = ii; }
    }
  }

  float acc[32];
#pragma unroll
  for (int k = 0; k < 32; ++k) acc[k] = 0.f;

  const float* xTb = xT + (size_t)b * HW * CIN;

  C4 L0, L1, L2;
  // prologue: chunk 0 load + reduce to LDS
  gload(xTb, i0, 0, L0);
  gload(xTb, i1, 0, L1);
  if (has3) gload(xTb, i2, 0, L2);
  redw(L0, g0, xlds + tid);
  redw(L1, g1, xlds + tid + 256);
  if (has3) redw(L2, g2, xlds + tid + 512);

  for (int cc = 0; cc < 16; ++cc) {
    __syncthreads();               // chunk cc's LDS writes visible
    // ---- issue chunk cc+1's loads into registers (latency hides in GEMM) --
    if (cc < 15) {
      const int c0n = (cc + 1) * 4;
      gload(xTb, i0, c0n, L0);
      gload(xTb, i1, c0n, L1);
      if (has3) gload(xTb, i2, c0n, L2);
    }
    // ---- GEMM on chunk cc: acc[k] += w[o][cg][n] * xoff[cg][n][lane] ----
#pragma unroll
    for (int c = 0; c < 4; ++c) {
      const int cg = cc * 4 + c;
#pragma unroll
      for (int n = 0; n < 9; ++n) {
        float xv = xlds[c * 576 + n * 64 + lane];
        const float* wr = wPu + (n * 64 + cg) * 128;   // wave-uniform addr
#pragma unroll
        for (int k = 0; k < 32; ++k)
          acc[k] = fmaf(wr[k], xv, acc[k]);
      }
    }
    __syncthreads();               // chunk cc fully consumed
    // ---- reduce prefetched chunk cc+1 into LDS ----
    if (cc < 15) {
      redw(L0, g0, xlds + tid);
      redw(L1, g1, xlds + tid + 256);
      if (has3) redw(L2, g2, xlds + tid + 512);
    }
  }

#pragma unroll
  for (int k = 0; k < 32; ++k) {
    out[((size_t)b * OC + ow_u + k) * HW + px0 + lane] = acc[k];
  }
}

extern "C" void kernel_launch(void* const* d_in, const int* in_sizes, int n_in,
                              void* d_out, int out_size, void* d_ws, size_t ws_size,
                              hipStream_t stream) {
  const float* x      = (const float*)d_in[0];  // (8,64,128,128)
  const float* w_conv = (const float*)d_in[1];  // (128,64,3,3)
  const float* w_p    = (const float*)d_in[2];  // (18,64,3,3)
  const float* b_p    = (const float*)d_in[3];  // (18,)
  float* outp = (float*)d_out;                  // (8,128,128,128)
  float* ws   = (float*)d_ws;                   // needs >= 52.8 MB

  float* wT   = ws + WT_OFF;
  float* wP   = ws + WP_OFF;
  float* offp = ws + OFF_OFF;
  float* xT   = ws + XT_OFF;

  repack_kernel<<<333, 256, 0, stream>>>(w_conv, w_p, wP, wT);
  transpose_kernel<<<dim3(256, 8), 256, 0, stream>>>(x, xT);
  offs_kernel<<<dim3(64, 8, 2), 256, 0, stream>>>(x, wT, offp);
  main_kernel<<<dim3(256, 8), 256, 0, stream>>>(xT, wP, offp, b_p, outp);
}